// Round 9
// baseline (144.203 us; speedup 1.0000x reference)
//
#include <hip/hip_runtime.h>
#include <math.h>

// Problem constants
#define B_    1024
#define D_    768
#define C_    150
#define P_    64
#define TWOD  1536
#define NCLS  151   // C+1
#define CPAD  256   // partial row: 0..150 logits, 151..191 junk, 192..255 u

// fused_tile: 128b x 64c per block, 8x4/thr, e split 8 ways x 2 phases of 96
#define ECHUNKS 8
#define ECHUNK  192
#define EPHASE  96

// gemm_all: 64x128 tile, BK=32, bf16 LDS stride 40 (2-way banks)
#define ASTR  40
// u-path LDS stride (halves): 120 -> 240B rows, 16B aligned
#define USTRU 120
// pair_loss LDS stride (halves)
#define USTR  72

// Workspace layout (float offsets)
#define OFF_MH      0                                   // half[150*1536]
#define OFF_XH      (OFF_MH + (C_ * TWOD) / 2)          // half[1024*1536]
#define OFF_PARTIAL (OFF_XH + (B_ * TWOD) / 2)          // fp32[8*1024*256]
#define OFF_UHF     (OFF_PARTIAL + ECHUNKS * B_ * CPAD) // half[1024*64]
#define OFF_SQN     (OFF_UHF + (B_ * P_) / 2)
#define OFF_CLS     (OFF_SQN + B_)
#define OFF_PAIR    (OFF_CLS + B_)
// end ~3.1M floats ~ 12.5 MB

typedef __bf16    bfx8   __attribute__((ext_vector_type(8)));
typedef _Float16  fp16x8 __attribute__((ext_vector_type(8)));
typedef _Float16  h2v    __attribute__((ext_vector_type(2)));
typedef float     f32x4  __attribute__((ext_vector_type(4)));

__device__ inline ushort f2bf(float f) {
    union { float f; unsigned u; } c; c.f = f;
    unsigned r = c.u + 0x7fffu + ((c.u >> 16) & 1u);
    return (ushort)(r >> 16);
}
__device__ inline ushort f2h(float f) {
    _Float16 h = (_Float16)f;
    return __builtin_bit_cast(ushort, h);
}
// pack two floats into one packed-f16 pair
__device__ inline unsigned pack2h(float a, float b) {
    h2v v = {(_Float16)a, (_Float16)b};
    return __builtin_bit_cast(unsigned, v);
}
// s = max(a + m, 0) on packed f16 pairs (v_pk_add_f16 + v_pk_max_f16)
__device__ inline unsigned addrelu2(unsigned a, unsigned m) {
    h2v s = __builtin_bit_cast(h2v, a) + __builtin_bit_cast(h2v, m);
    h2v z = {(_Float16)0.f, (_Float16)0.f};
    s = __builtin_elementwise_max(s, z);
    return __builtin_bit_cast(unsigned, s);
}
__device__ inline unsigned relu2(unsigned a) {
    h2v s = __builtin_bit_cast(h2v, a);
    h2v z = {(_Float16)0.f, (_Float16)0.f};
    s = __builtin_elementwise_max(s, z);
    return __builtin_bit_cast(unsigned, s);
}
// acc += dot(f16pair a, f16pair b) in fp32  (v_dot2_f32_f16)
__device__ inline float dot2acc(unsigned a, unsigned b, float c) {
    return __builtin_amdgcn_fdot2(__builtin_bit_cast(h2v, a),
                                  __builtin_bit_cast(h2v, b), c, false);
}
// convert float4 pair -> 8 bf16 in uint4
__device__ inline uint4 cvt8bf(float4 a, float4 b) {
    ushort o[8];
    o[0] = f2bf(a.x); o[1] = f2bf(a.y); o[2] = f2bf(a.z); o[3] = f2bf(a.w);
    o[4] = f2bf(b.x); o[5] = f2bf(b.y); o[6] = f2bf(b.z); o[7] = f2bf(b.w);
    return *(const uint4*)&o[0];
}

// ---------------------------------------------------------------------------
// K1: merged MFMA GEMM (x-gemm + mem-gemm), fp32 in / f16 out, in-register
// fp32->bf16 staging. blocks [0,192): xh = x @ Wx^T + fc_b ;
// blocks [192,228): mh = mem @ Wm^T. 64x128 tile, BK=32, register prefetch.
// ---------------------------------------------------------------------------
__global__ __launch_bounds__(256) void gemm_all(
    const float* __restrict__ xf, const float* __restrict__ memf,
    const float* __restrict__ fcw, const float* __restrict__ fc_b,
    ushort* __restrict__ xh, ushort* __restrict__ mh)
{
    __shared__ ushort As[64 * ASTR];
    __shared__ ushort Bs[128 * ASTR];
    const int id = blockIdx.x;
    const int t  = threadIdx.x;

    const float* A; ushort* Out; int M, m0, n0, koff; bool xblk;
    if (id < 192) {
        xblk = true;  A = xf;   Out = xh; M = B_;
        m0 = (id & 15) * 64; n0 = (id >> 4) * 128; koff = 0;
    } else {
        int q = id - 192;
        xblk = false; A = memf; Out = mh; M = C_;
        m0 = (q % 3) * 64; n0 = (q / 3) * 128; koff = D_;
    }

    const int wave = t >> 6, lane = t & 63;
    const int wm = (wave & 1) * 32, wn = (wave >> 1) * 64;
    const int fm = lane & 15, quad = lane >> 4;

    const int row_a = t >> 2, qa = (t & 3) * 8;
    const int ar = min(m0 + row_a, M - 1);
    const float* Arow  = A + (size_t)ar * D_ + qa;
    const float* Brow0 = fcw + (size_t)(n0 + row_a) * TWOD + koff + qa;
    const float* Brow1 = Brow0 + (size_t)64 * TWOD;

    f32x4 acc[2][4];
#pragma unroll
    for (int j = 0; j < 4; ++j) {
        float bv = xblk ? fc_b[n0 + wn + j * 16 + fm] : 0.f;
#pragma unroll
        for (int i = 0; i < 2; ++i)
            acc[i][j] = (f32x4){bv, bv, bv, bv};
    }

    float4 pa0  = *(const float4*)(Arow),      pa1 = *(const float4*)(Arow + 4);
    float4 pb00 = *(const float4*)(Brow0),    pb01 = *(const float4*)(Brow0 + 4);
    float4 pb10 = *(const float4*)(Brow1),    pb11 = *(const float4*)(Brow1 + 4);

    for (int k0 = 0; k0 < D_; k0 += 32) {
        uint4 va  = cvt8bf(pa0, pa1);
        uint4 vb0 = cvt8bf(pb00, pb01);
        uint4 vb1 = cvt8bf(pb10, pb11);
        __syncthreads();   // prev frag reads done
        *(uint4*)&As[row_a * ASTR + qa] = va;
        *(uint4*)&Bs[row_a * ASTR + qa] = vb0;
        *(uint4*)&Bs[(64 + row_a) * ASTR + qa] = vb1;
        __syncthreads();
        if (k0 + 32 < D_) {
            pa0  = *(const float4*)(Arow + k0 + 32);
            pa1  = *(const float4*)(Arow + k0 + 36);
            pb00 = *(const float4*)(Brow0 + k0 + 32);
            pb01 = *(const float4*)(Brow0 + k0 + 36);
            pb10 = *(const float4*)(Brow1 + k0 + 32);
            pb11 = *(const float4*)(Brow1 + k0 + 36);
        }
        bfx8 af[2], bf[4];
#pragma unroll
        for (int i = 0; i < 2; ++i)
            af[i] = *(const bfx8*)&As[(wm + i * 16 + fm) * ASTR + quad * 8];
#pragma unroll
        for (int j = 0; j < 4; ++j)
            bf[j] = *(const bfx8*)&Bs[(wn + j * 16 + fm) * ASTR + quad * 8];
#pragma unroll
        for (int i = 0; i < 2; ++i)
#pragma unroll
            for (int j = 0; j < 4; ++j)
                acc[i][j] = __builtin_amdgcn_mfma_f32_16x16x32_bf16(
                    af[i], bf[j], acc[i][j], 0, 0, 0);
    }

#pragma unroll
    for (int i = 0; i < 2; ++i)
#pragma unroll
        for (int j = 0; j < 4; ++j)
#pragma unroll
            for (int r = 0; r < 4; ++r) {
                int row = m0 + wm + i * 16 + quad * 4 + r;
                int col = n0 + wn + j * 16 + fm;
                if (row < M) Out[(size_t)row * TWOD + col] = f2h(acc[i][j][r]);
            }
}

// ---------------------------------------------------------------------------
// K2: fused tile (f16), 192-e chunk per z in 2 phases of 96.
// y<3: elementwise partial[z][b][c] = sum relu(xh+m)*p1 via pk_f16 + dot2.
// y==3: MFMA f16 u-projection partial[z][b][192+n] = sum relu(xh)*p2.
// ---------------------------------------------------------------------------
__global__ __launch_bounds__(256) void fused_tile(
    const ushort* __restrict__ xh, const ushort* __restrict__ mh,
    const float* __restrict__ p1w, const float* __restrict__ p2w,
    float* __restrict__ partial)
{
    __shared__ __align__(16) char smem[46080];
    const int t  = threadIdx.x;
    const int b0 = blockIdx.x * 128;
    const int z  = blockIdx.z;
    const int e0 = z * ECHUNK;

    if (blockIdx.y == 3) {
        // -------- MFMA f16 u-projection path --------
        ushort* Au = (ushort*)smem;                 // 128 x USTRU halves
        ushort* Wu = (ushort*)(smem + 30720);       // 64 x USTRU halves
        const int wave = t >> 6, lane = t & 63;
        const int fm = lane & 15, quad = lane >> 4;

        f32x4 uacc[2][4];
#pragma unroll
        for (int i = 0; i < 2; ++i)
#pragma unroll
            for (int j = 0; j < 4; ++j) uacc[i][j] = (f32x4){0.f, 0.f, 0.f, 0.f};

        for (int ph = 0; ph < 2; ++ph) {
            const int ep0 = e0 + ph * EPHASE;
            // stage relu(xh) f16 : 128 rows x 96 k
            const int row = t >> 1, kh = (t & 1) * 48;
            const ushort* src = xh + (size_t)(b0 + row) * TWOD + ep0 + kh;
            uint4 v[6];
#pragma unroll
            for (int i = 0; i < 6; ++i) v[i] = *(const uint4*)&src[i * 8];
            // stage p2 (fp32 -> f16): 64 rows x 96 k, 4 thr/row x 24 each
            const int prow = t >> 2, ks = (t & 3) * 24;
            const float* pw = p2w + (size_t)prow * TWOD + ep0 + ks;
            float4 w[6];
#pragma unroll
            for (int i = 0; i < 6; ++i) w[i] = *(const float4*)&pw[i * 4];
            __syncthreads();   // prev phase frag reads done
#pragma unroll
            for (int i = 0; i < 6; ++i) {
                v[i].x = relu2(v[i].x); v[i].y = relu2(v[i].y);
                v[i].z = relu2(v[i].z); v[i].w = relu2(v[i].w);
                *(uint4*)&Au[row * USTRU + kh + i * 8] = v[i];
            }
#pragma unroll
            for (int i = 0; i < 3; ++i) {
                uint4 o;
                o.x = pack2h(w[2*i].x, w[2*i].y);
                o.y = pack2h(w[2*i].z, w[2*i].w);
                o.z = pack2h(w[2*i+1].x, w[2*i+1].y);
                o.w = pack2h(w[2*i+1].z, w[2*i+1].w);
                *(uint4*)&Wu[prow * USTRU + ks + i * 8] = o;
            }
            __syncthreads();

#pragma unroll
            for (int k0 = 0; k0 < EPHASE; k0 += 32) {
                fp16x8 af[2], bf[4];
#pragma unroll
                for (int i = 0; i < 2; ++i)
                    af[i] = *(const fp16x8*)&Au[(wave * 32 + i * 16 + fm) * USTRU + k0 + quad * 8];
#pragma unroll
                for (int j = 0; j < 4; ++j)
                    bf[j] = *(const fp16x8*)&Wu[(j * 16 + fm) * USTRU + k0 + quad * 8];
#pragma unroll
                for (int i = 0; i < 2; ++i)
#pragma unroll
                    for (int j = 0; j < 4; ++j)
                        uacc[i][j] = __builtin_amdgcn_mfma_f32_16x16x32_f16(
                            af[i], bf[j], uacc[i][j], 0, 0, 0);
            }
        }
#pragma unroll
        for (int i = 0; i < 2; ++i)
#pragma unroll
            for (int j = 0; j < 4; ++j)
#pragma unroll
                for (int r = 0; r < 4; ++r) {
                    int row = b0 + wave * 32 + i * 16 + quad * 4 + r;
                    partial[((size_t)z * B_ + row) * CPAD + 192 + j * 16 + fm] =
                        uacc[i][j][r];
                }
        return;
    }

    // -------- elementwise f16 path: cols c0..c0+63 (c0 in {0,64,128}) -----
    unsigned* xT = (unsigned*)smem;             // [48 e-pairs][128 b]
    unsigned* mT = (unsigned*)(smem + 24576);   // [48][64 c]
    unsigned* wT = (unsigned*)(smem + 36864);   // [48]
    const int c0 = blockIdx.y * 64;
    const int tm = t & 15, tn = t >> 4;

    float acc[8][4] = {};

    for (int ph = 0; ph < 2; ++ph) {
        const int ep0 = e0 + ph * EPHASE;
        // stage x: 2 thr/row, 48 halves each
        const int row = t >> 1, phh = (t & 1) * 48;
        const ushort* src = xh + (size_t)(b0 + row) * TWOD + ep0 + phh;
        uint4 v[6];
#pragma unroll
        for (int i = 0; i < 6; ++i) v[i] = *(const uint4*)&src[i * 8];
        // stage m: 4 thr/col, 24 halves each
        const int col = t & 63, seg = t >> 6;
        const int gc  = c0 + col;
        uint4 mv[3];
        if (gc < C_) {
            const ushort* msrc = mh + (size_t)gc * TWOD + ep0 + seg * 24;
#pragma unroll
            for (int i = 0; i < 3; ++i) mv[i] = *(const uint4*)&msrc[i * 8];
        } else {
#pragma unroll
            for (int i = 0; i < 3; ++i) mv[i] = make_uint4(0, 0, 0, 0);
        }
        // stage w (p1 fp32): 12 thr x 8 floats
        float4 w0, w1;
        if (t < 12) {
            w0 = *(const float4*)&p1w[ep0 + t * 8];
            w1 = *(const float4*)&p1w[ep0 + t * 8 + 4];
        }
        __syncthreads();   // prev phase LDS reads done
#pragma unroll
        for (int i = 0; i < 6; ++i) {
            const int ep = (t & 1) * 24 + i * 4;
            xT[(ep + 0) * 128 + row] = v[i].x;
            xT[(ep + 1) * 128 + row] = v[i].y;
            xT[(ep + 2) * 128 + row] = v[i].z;
            xT[(ep + 3) * 128 + row] = v[i].w;
        }
#pragma unroll
        for (int i = 0; i < 3; ++i) {
            const int ep = seg * 12 + i * 4;
            mT[(ep + 0) * 64 + col] = mv[i].x;
            mT[(ep + 1) * 64 + col] = mv[i].y;
            mT[(ep + 2) * 64 + col] = mv[i].z;
            mT[(ep + 3) * 64 + col] = mv[i].w;
        }
        if (t < 12) {
            wT[t * 4 + 0] = pack2h(w0.x, w0.y);
            wT[t * 4 + 1] = pack2h(w0.z, w0.w);
            wT[t * 4 + 2] = pack2h(w1.x, w1.y);
            wT[t * 4 + 3] = pack2h(w1.z, w1.w);
        }
        __syncthreads();

#pragma unroll 4
        for (int ep = 0; ep < 48; ++ep) {
            uint4 a0 = *(const uint4*)&xT[ep * 128 + tm * 8];
            uint4 a1 = *(const uint4*)&xT[ep * 128 + tm * 8 + 4];
            uint4 mj = *(const uint4*)&mT[ep * 64 + tn * 4];
            const unsigned wv = wT[ep];
            const unsigned aa[8] = {a0.x, a0.y, a0.z, a0.w, a1.x, a1.y, a1.z, a1.w};
            const unsigned mm[4] = {mj.x, mj.y, mj.z, mj.w};
#pragma unroll
            for (int i = 0; i < 8; ++i)
#pragma unroll
                for (int j = 0; j < 4; ++j)
                    acc[i][j] = dot2acc(addrelu2(aa[i], mm[j]), wv, acc[i][j]);
        }
    }

#pragma unroll
    for (int i = 0; i < 8; ++i) {
        const int gb = b0 + tm * 8 + i;
        float4 v = make_float4(acc[i][0], acc[i][1], acc[i][2], acc[i][3]);
        *(float4*)&partial[((size_t)z * B_ + gb) * CPAD + c0 + tn * 4] = v;
    }
}

// ---------------------------------------------------------------------------
// K3: per-row reduce of partials + bias, u-normalize (-> f16) + cls loss.
// ---------------------------------------------------------------------------
__global__ __launch_bounds__(256) void reduce_row(
    const float* __restrict__ partial,
    const float* __restrict__ p1b, const float* __restrict__ p2b,
    const int* __restrict__ lb,
    ushort* __restrict__ uhf, float* __restrict__ sqn,
    float* __restrict__ clsbuf)
{
    const int b = blockIdx.x, t = threadIdx.x;
    float v = 0.f;
#pragma unroll
    for (int z = 0; z < ECHUNKS; ++z)
        v += partial[((size_t)z * B_ + b) * CPAD + t];
    if (t < NCLS)       v += p1b[0];
    else if (t >= 192)  v += p2b[t - 192];

    __shared__ float sval[256];
    sval[t] = v;
    __syncthreads();

    if (t < 64) {
        float uv = sval[192 + t];
        float s = uv * uv;
#pragma unroll
        for (int off = 32; off; off >>= 1) s += __shfl_xor(s, off);
        float inv = 1.f / fmaxf(sqrtf(s), 1e-12f);
        uhf[(size_t)b * P_ + t] = f2h(uv * inv);
        if (t == 0) sqn[b] = s * inv * inv;

        const int l = lb[b];
        float mx = -1e30f;
        for (int j = t; j < NCLS; j += 64)
            if (!(j == l && l < C_)) mx = fmaxf(mx, sval[j]);
#pragma unroll
        for (int off = 32; off; off >>= 1) mx = fmaxf(mx, __shfl_xor(mx, off));
        float se = 0.f;
        for (int j = t; j < NCLS; j += 64)
            if (!(j == l && l < C_)) se += expf(sval[j] - mx);
#pragma unroll
        for (int off = 32; off; off >>= 1) se += __shfl_xor(se, off);

        if (t == 0) {
            float l150  = sval[C_];
            float loss2 = mx + logf(se) - l150;
            float loss1 = 0.f;
            if (l < C_) {
                float a  = sval[l];
                float m2 = fmaxf(a, l150);
                loss1 = m2 - a + logf(expf(a - m2) + expf(l150 - m2));
            }
            clsbuf[b] = loss1 + loss2;
        }
    }
}

// ---------------------------------------------------------------------------
// K4: pairwise margin losses via f16 MFMA Gram tiles. 64x64 pairs per block.
// ---------------------------------------------------------------------------
__global__ __launch_bounds__(256) void pair_loss(
    const ushort* __restrict__ uhf, const float* __restrict__ sqn,
    const int* __restrict__ lb, float* __restrict__ pairpart)
{
    __shared__ ushort ui_s[64 * USTR];
    __shared__ ushort uj_s[64 * USTR];
    __shared__ float sni[64], snj[64];
    __shared__ int   li[64],  lj[64];
    __shared__ float red[4][4];

    const int t  = threadIdx.x;
    const int i0 = blockIdx.x * 64, j0 = blockIdx.y * 64;

    for (int idx = t; idx < 512; idx += 256) {
        int row = idx >> 3, ch = (idx & 7) * 8;
        *(uint4*)&ui_s[row * USTR + ch] =
            *(const uint4*)&uhf[(size_t)(i0 + row) * P_ + ch];
        *(uint4*)&uj_s[row * USTR + ch] =
            *(const uint4*)&uhf[(size_t)(j0 + row) * P_ + ch];
    }
    if (t < 64)       { sni[t] = sqn[i0 + t]; li[t] = lb[i0 + t]; }
    else if (t < 128) { int q = t - 64; snj[q] = sqn[j0 + q]; lj[q] = lb[j0 + q]; }
    __syncthreads();

    const int wave = t >> 6, lane = t & 63;
    const int n = lane & 15, quad = lane >> 4;
    const int iw = wave * 16;

    const fp16x8 af0 = *(const fp16x8*)&ui_s[(iw + n) * USTR + quad * 8];
    const fp16x8 af1 = *(const fp16x8*)&ui_s[(iw + n) * USTR + quad * 8 + 32];

    f32x4 acc[4];
#pragma unroll
    for (int jt = 0; jt < 4; ++jt) {
        const fp16x8 bf0 = *(const fp16x8*)&uj_s[(jt * 16 + n) * USTR + quad * 8];
        const fp16x8 bf1 = *(const fp16x8*)&uj_s[(jt * 16 + n) * USTR + quad * 8 + 32];
        acc[jt] = __builtin_amdgcn_mfma_f32_16x16x32_f16(
            af0, bf0, (f32x4){0.f, 0.f, 0.f, 0.f}, 0, 0, 0);
        acc[jt] = __builtin_amdgcn_mfma_f32_16x16x32_f16(
            af1, bf1, acc[jt], 0, 0, 0);
    }

    float ps = 0.f, pc = 0.f, ns = 0.f, nc = 0.f;
#pragma unroll
    for (int jt = 0; jt < 4; ++jt)
#pragma unroll
        for (int r = 0; r < 4; ++r) {
            const int il = iw + quad * 4 + r;
            const int jl = jt * 16 + n;
            float sq = sni[il] + snj[jl] - 2.f * acc[jt][r];
            float dist = sq > 0.f ? sqrtf(fmaxf(sq, 1e-16f)) : 0.f;
            bool same = (li[il] == lj[jl]);
            if (same) {
                if (i0 + il != j0 + jl) { ps += fmaxf(dist - 0.7f, 0.f); pc += 1.f; }
            } else {
                ns += fmaxf(1.4f - dist, 0.f); nc += 1.f;
            }
        }

#pragma unroll
    for (int off = 32; off; off >>= 1) {
        ps += __shfl_xor(ps, off); pc += __shfl_xor(pc, off);
        ns += __shfl_xor(ns, off); nc += __shfl_xor(nc, off);
    }
    if (lane == 0) { red[0][wave] = ps; red[1][wave] = pc;
                     red[2][wave] = ns; red[3][wave] = nc; }
    __syncthreads();
    if (t == 0) {
        float4 v;
        v.x = red[0][0] + red[0][1] + red[0][2] + red[0][3];
        v.y = red[1][0] + red[1][1] + red[1][2] + red[1][3];
        v.z = red[2][0] + red[2][1] + red[2][2] + red[2][3];
        v.w = red[3][0] + red[3][1] + red[3][2] + red[3][3];
        *(float4*)&pairpart[(size_t)(blockIdx.y * 16 + blockIdx.x) * 4] = v;
    }
}

// ---------------------------------------------------------------------------
// K5: finalize — reduce clsbuf[1024] and pairpart[256][4].
// ---------------------------------------------------------------------------
__global__ __launch_bounds__(256) void finalize(
    const float* __restrict__ clsbuf, const float* __restrict__ pairpart,
    float* __restrict__ out)
{
    __shared__ float red[5][4];
    const int t = threadIdx.x;
    float c = clsbuf[t] + clsbuf[t + 256] + clsbuf[t + 512] + clsbuf[t + 768];
    float4 pp = *(const float4*)&pairpart[(size_t)t * 4];
    float ps = pp.x, pc = pp.y, ns = pp.z, nc = pp.w;
#pragma unroll
    for (int off = 32; off; off >>= 1) {
        c  += __shfl_xor(c, off);
        ps += __shfl_xor(ps, off); pc += __shfl_xor(pc, off);
        ns += __shfl_xor(ns, off); nc += __shfl_xor(nc, off);
    }
    const int wave = t >> 6, lane = t & 63;
    if (lane == 0) { red[0][wave] = c; red[1][wave] = ps; red[2][wave] = pc;
                     red[3][wave] = ns; red[4][wave] = nc; }
    __syncthreads();
    if (t == 0) {
        float C = 0.f, PS = 0.f, PC = 0.f, NS = 0.f, NC = 0.f;
#pragma unroll
        for (int w = 0; w < 4; ++w) {
            C += red[0][w]; PS += red[1][w]; PC += red[2][w];
            NS += red[3][w]; NC += red[4][w];
        }
        out[0] = C / (float)B_ + PS / fmaxf(PC, 1.f) + NS / fmaxf(NC, 1.f);
    }
}

extern "C" void kernel_launch(void* const* d_in, const int* in_sizes, int n_in,
                              void* d_out, int out_size, void* d_ws, size_t ws_size,
                              hipStream_t stream)
{
    const float* x    = (const float*)d_in[0];
    const int*   lb   = (const int*)d_in[1];
    const float* mem  = (const float*)d_in[2];
    const float* fc_w = (const float*)d_in[3];
    const float* fc_b = (const float*)d_in[4];
    const float* p1w  = (const float*)d_in[5];
    const float* p1b  = (const float*)d_in[6];
    const float* p2w  = (const float*)d_in[7];
    const float* p2b  = (const float*)d_in[8];

    float* ws       = (float*)d_ws;
    ushort* mh      = (ushort*)(ws + OFF_MH);
    ushort* xh      = (ushort*)(ws + OFF_XH);
    float* partials = ws + OFF_PARTIAL;
    ushort* uhf     = (ushort*)(ws + OFF_UHF);
    float* sqn      = ws + OFF_SQN;
    float* clsbuf   = ws + OFF_CLS;
    float* pairpart = ws + OFF_PAIR;

    // K1: merged gemms (fp32 in, in-register bf16 staging) -> f16 xh, mh
    gemm_all<<<228, 256, 0, stream>>>(x, mem, fc_w, fc_b, xh, mh);
    // K2: fused elementwise logits partials (f16 dot2) + MFMA f16 u-partials
    fused_tile<<<dim3(8, 4, ECHUNKS), 256, 0, stream>>>(xh, mh, p1w, p2w,
                                                        partials);
    // K3: reduce partials + bias, normalize u (f16), classification loss
    reduce_row<<<B_, 256, 0, stream>>>(partials, p1b, p2b, lb, uhf, sqn, clsbuf);
    // K4: pairwise margin losses
    pair_loss<<<dim3(16, 16), 256, 0, stream>>>(uhf, sqn, lb, pairpart);
    // K5: final reduce + write scalar output
    finalize<<<1, 256, 0, stream>>>(clsbuf, pairpart, (float*)d_out);
}